// Round 4
// baseline (1526.990 us; speedup 1.0000x reference)
//
#include <hip/hip_runtime.h>
#include <cstdint>
#include <cstddef>

typedef __bf16 bf16x8 __attribute__((ext_vector_type(8)));
typedef float f32x4 __attribute__((ext_vector_type(4)));
typedef unsigned short u16;

#define MFMA_B16(a, b, c) __builtin_amdgcn_mfma_f32_16x16x32_bf16((a), (b), (c), 0, 0, 0)

__device__ __forceinline__ u16 f2bf(float f) {
  unsigned u = __builtin_bit_cast(unsigned, f);
  u += 0x7fffu + ((u >> 16) & 1u);
  return (u16)(u >> 16);
}
__device__ __forceinline__ float bf2f(u16 h) {
  unsigned u = ((unsigned)h) << 16;
  return __builtin_bit_cast(float, u);
}

// ---------------- problem constants ----------------
// DIM=2048, HEADS=16, DIM_HEAD=64, ATTN_INNER=1024, FF_INNER=8192
// fused width = 1024 + 64 + 64 + 2*8192 = 17536 cols:
//   q[0,1024) k[1024,1088) v[1088,1152) ff_x[1152,9344+64) ff_gate[...,17536)
// B=2, N=2048 -> 4096 rows.

// ---------------- workspace layout (bytes) ----------------
static const size_t OFF_WFT   = 0;                                  // w_fused^T   17536x2048 bf16
static const size_t OFF_WAOT  = OFF_WFT   + (size_t)17536*2048*2;   // w_attn_out^T 2048x1024 bf16
static const size_t OFF_WFOT  = OFF_WAOT  + (size_t)2048*1024*2;    // w_ff_out^T  2048x8192 bf16
static const size_t OFF_XN    = OFF_WFOT  + (size_t)2048*8192*2;    // xn          4096x2048 bf16
static const size_t OFF_XA    = OFF_XN    + (size_t)4096*2048*2;    // xa          4096x24 f32 (q|k|v)
static const size_t OFF_QKV   = OFF_XA    + (size_t)4096*24*4;      // qkv         4096x1152 f32
static const size_t OFF_FFRAW = OFF_QKV   + (size_t)4096*1152*4;    // ffraw       4096x16384 bf16 (x|gate), silu in-place into x half
static const size_t OFF_QH    = OFF_FFRAW + (size_t)4096*16384*2;   // q           [b][h][n][64] bf16
static const size_t OFF_KH    = OFF_QH    + (size_t)4194304*2;      // k           [b][n][64] bf16
static const size_t OFF_VT    = OFF_KH    + (size_t)2*2048*64*2;    // v^T         [b][64][n] bf16
static const size_t OFF_AIN   = OFF_VT    + (size_t)2*2048*64*2;    // attn out    [b][n][1024] bf16
static const size_t OFF_OA    = OFF_AIN   + (size_t)4096*1024*2;    // oa          4096x8 f32
static const size_t OFF_COS   = OFF_OA    + (size_t)4096*8*4;       // cos table   2048x32 f32
static const size_t OFF_SIN   = OFF_COS   + (size_t)2048*32*4;      // sin table   2048x32 f32
static const size_t WS_NEED   = OFF_SIN   + (size_t)2048*32*4;      // ~285 MB

// ---------------- transpose + cast f32 -> bf16 ----------------
// src: R x C f32 (row-major) -> dst: C x R bf16 (row-major)
__global__ __launch_bounds__(256) void transpose_cast_kernel(const float* __restrict__ src,
                                                             u16* __restrict__ dst, int R, int C) {
  __shared__ float tile[32][33];
  const int c0 = blockIdx.x * 32, r0 = blockIdx.y * 32;
  const int tx = threadIdx.x, ty = threadIdx.y;  // 32 x 8
#pragma unroll
  for (int i = 0; i < 4; ++i)
    tile[ty + i * 8][tx] = src[(size_t)(r0 + ty + i * 8) * C + c0 + tx];
  __syncthreads();
#pragma unroll
  for (int i = 0; i < 4; ++i)
    dst[(size_t)(c0 + ty + i * 8) * R + r0 + tx] = f2bf(tile[tx][ty + i * 8]);
}

// ---------------- RoPE cos/sin tables ----------------
__global__ __launch_bounds__(64) void rope_table_kernel(float* __restrict__ cosT, float* __restrict__ sinT) {
  const int n = blockIdx.x, t = threadIdx.x;
  if (t < 32) {
    const float invf = expf(-((float)t * (1.0f / 32.0f)) * 9.210340371976184f);  // 10000^(-t/32)
    const float ang = (float)n * invf;
    cosT[n * 32 + t] = cosf(ang);
    sinT[n * 32 + t] = sinf(ang);
  }
}

// ---------------- LayerNorm -> bf16 ----------------
__global__ __launch_bounds__(256) void layernorm_kernel(const float* __restrict__ x,
                                                        const float* __restrict__ gamma,
                                                        u16* __restrict__ xn) {
  const int row = blockIdx.x, t = threadIdx.x;
  const float* xr = x + (size_t)row * 2048;
  float v[8];
  const float4 a0 = *(const float4*)(xr + t * 8);
  const float4 a1 = *(const float4*)(xr + t * 8 + 4);
  v[0] = a0.x; v[1] = a0.y; v[2] = a0.z; v[3] = a0.w;
  v[4] = a1.x; v[5] = a1.y; v[6] = a1.z; v[7] = a1.w;
  float s = 0.f, sq = 0.f;
#pragma unroll
  for (int j = 0; j < 8; ++j) { s += v[j]; sq += v[j] * v[j]; }
#pragma unroll
  for (int o = 32; o > 0; o >>= 1) { s += __shfl_xor(s, o); sq += __shfl_xor(sq, o); }
  __shared__ float red[8];
  if ((t & 63) == 0) { red[(t >> 6) * 2] = s; red[(t >> 6) * 2 + 1] = sq; }
  __syncthreads();
  s = red[0] + red[2] + red[4] + red[6];
  sq = red[1] + red[3] + red[5] + red[7];
  const float mu = s * (1.0f / 2048.0f);
  const float var = sq * (1.0f / 2048.0f) - mu * mu;
  const float rstd = rsqrtf(var + 1e-5f);
  const float* g = gamma + t * 8;
  u16 o8[8];
#pragma unroll
  for (int j = 0; j < 8; ++j) o8[j] = f2bf((v[j] - mu) * rstd * g[j]);
  *(ushort4*)(xn + (size_t)row * 2048 + t * 8) = make_ushort4(o8[0], o8[1], o8[2], o8[3]);
  *(ushort4*)(xn + (size_t)row * 2048 + t * 8 + 4) = make_ushort4(o8[4], o8[5], o8[6], o8[7]);
}

// ---------------- xa = xn @ [a_q | a_k | a_v]  (4096 x 24) ----------------
__global__ __launch_bounds__(256) void xa3_kernel(const u16* __restrict__ xn, const float* __restrict__ a_q,
                                                  const float* __restrict__ a_k, const float* __restrict__ a_v,
                                                  float* __restrict__ xa) {
  const int row = blockIdx.x, t = threadIdx.x;
  float acc[24];
#pragma unroll
  for (int j = 0; j < 24; ++j) acc[j] = 0.f;
  const u16* xr = xn + (size_t)row * 2048;
  for (int k = t; k < 2048; k += 256) {
    const float xv = bf2f(xr[k]);
    const float* aq = a_q + k * 8;
    const float* ak = a_k + k * 8;
    const float* av = a_v + k * 8;
#pragma unroll
    for (int j = 0; j < 8; ++j) {
      acc[j] += xv * aq[j];
      acc[8 + j] += xv * ak[j];
      acc[16 + j] += xv * av[j];
    }
  }
#pragma unroll
  for (int j = 0; j < 24; ++j) {
    float vv = acc[j];
#pragma unroll
    for (int o = 32; o > 0; o >>= 1) vv += __shfl_xor(vv, o);
    acc[j] = vv;
  }
  __shared__ float red[4][24];
  if ((t & 63) == 0) {
#pragma unroll
    for (int j = 0; j < 24; ++j) red[t >> 6][j] = acc[j];
  }
  __syncthreads();
  if (t < 24) xa[(size_t)row * 24 + t] = red[0][t] + red[1][t] + red[2][t] + red[3][t];
}

// ---------------- shared GEMM inner phase ----------------
// Block tile 128(M) x 64(N), BK=32, 4 waves in 2x2; wave tile 64x32 (4x2 MFMA 16x16x32).
// A row-major [M][K] bf16; B given TRANSPOSED row-major [N][K] bf16.
__device__ __forceinline__ void gemm_phase(const u16* __restrict__ Ab, int astride,
                                           const u16* __restrict__ Bb, int bstride, int K,
                                           u16* lds_a, u16* lds_b, f32x4 (&acc)[4][2],
                                           int t, int wr, int wc, int lq, int g) {
  const int ar0 = t >> 2;
  const int as0 = (t & 3) * 8;
  for (int k0 = 0; k0 < K; k0 += 32) {
    const uint4 va0 = *(const uint4*)(Ab + (size_t)ar0 * astride + k0 + as0);
    const uint4 va1 = *(const uint4*)(Ab + (size_t)(ar0 + 64) * astride + k0 + as0);
    const uint4 vb = *(const uint4*)(Bb + (size_t)ar0 * bstride + k0 + as0);
    __syncthreads();
    *(uint4*)(lds_a + t * 8) = va0;
    *(uint4*)(lds_a + (t + 256) * 8) = va1;
    *(uint4*)(lds_b + t * 8) = vb;
    __syncthreads();
    bf16x8 af[4], bfr[2];
#pragma unroll
    for (int mi = 0; mi < 4; ++mi)
      af[mi] = *(const bf16x8*)(lds_a + (wr * 64 + mi * 16 + lq) * 32 + g * 8);
#pragma unroll
    for (int ni = 0; ni < 2; ++ni)
      bfr[ni] = *(const bf16x8*)(lds_b + (wc * 32 + ni * 16 + lq) * 32 + g * 8);
#pragma unroll
    for (int mi = 0; mi < 4; ++mi)
#pragma unroll
      for (int ni = 0; ni < 2; ++ni)
        acc[mi][ni] = MFMA_B16(af[mi], bfr[ni], acc[mi][ni]);
  }
}

// ---------------- fused GEMM: xn @ w_fused (+LoRA on qkv cols) ----------------
__global__ __launch_bounds__(256) void gemm_fused_kernel(const u16* __restrict__ A, const u16* __restrict__ BT,
                                                         float* __restrict__ qkv, u16* __restrict__ ffraw,
                                                         const float* __restrict__ xa,
                                                         const float* __restrict__ b_q,
                                                         const float* __restrict__ b_k,
                                                         const float* __restrict__ b_v) {
  __shared__ u16 lds_a[128 * 32];
  __shared__ u16 lds_b[64 * 32];
  const int bm = blockIdx.x, bn = blockIdx.y;
  const int t = threadIdx.x, w = t >> 6, l = t & 63;
  const int wr = w >> 1, wc = w & 1, lq = l & 15, g = l >> 4;
  f32x4 acc[4][2];
  const f32x4 z = {0.f, 0.f, 0.f, 0.f};
#pragma unroll
  for (int mi = 0; mi < 4; ++mi)
#pragma unroll
    for (int ni = 0; ni < 2; ++ni) acc[mi][ni] = z;
  gemm_phase(A + (size_t)bm * 128 * 2048, 2048, BT + (size_t)bn * 64 * 2048, 2048, 2048,
             lds_a, lds_b, acc, t, wr, wc, lq, g);
  const int rowbase = bm * 128 + wr * 64;
  const int colbase = bn * 64 + wc * 32;
  if (bn < 18) {  // qkv region with LoRA epilogue
#pragma unroll
    for (int mi = 0; mi < 4; ++mi)
#pragma unroll
      for (int ni = 0; ni < 2; ++ni)
#pragma unroll
        for (int r = 0; r < 4; ++r) {
          const int grow = rowbase + mi * 16 + g * 4 + r;
          const int gcol = colbase + ni * 16 + lq;
          const float* xar = xa + (size_t)grow * 24;
          float add = 0.f;
          if (gcol < 1024) {
            const float* bp = b_q + gcol;
#pragma unroll
            for (int j = 0; j < 8; ++j) add += xar[j] * bp[j * 1024];
          } else if (gcol < 1088) {
            const float* bp = b_k + (gcol - 1024);
#pragma unroll
            for (int j = 0; j < 8; ++j) add += xar[8 + j] * bp[j * 64];
          } else {
            const float* bp = b_v + (gcol - 1088);
#pragma unroll
            for (int j = 0; j < 8; ++j) add += xar[16 + j] * bp[j * 64];
          }
          qkv[(size_t)grow * 1152 + gcol] = acc[mi][ni][r] + add;
        }
  } else {  // ff region -> raw bf16
#pragma unroll
    for (int mi = 0; mi < 4; ++mi)
#pragma unroll
      for (int ni = 0; ni < 2; ++ni)
#pragma unroll
        for (int r = 0; r < 4; ++r) {
          const int grow = rowbase + mi * 16 + g * 4 + r;
          const int gcol = colbase + ni * 16 + lq - 1152;
          ffraw[(size_t)grow * 16384 + gcol] = f2bf(acc[mi][ni][r]);
        }
  }
}

// ---------------- RoPE + scale + relayout q/k/v ----------------
__global__ __launch_bounds__(256) void rope_qkv_kernel(const float* __restrict__ qkv,
                                                       const float* __restrict__ cosT,
                                                       const float* __restrict__ sinT,
                                                       u16* __restrict__ qh, u16* __restrict__ kh,
                                                       u16* __restrict__ vt) {
  const int row = blockIdx.x;  // b*2048+n
  const int y = blockIdx.y;
  const int t = threadIdx.x;
  const int b = row >> 11, n = row & 2047;
  const float* qr = qkv + (size_t)row * 1152;
  const float* cn = cosT + n * 32;
  const float* sn = sinT + n * 32;
  if (y < 4) {  // q cols
    const int col = y * 256 + t;
    const int hh = col >> 6, d = col & 63;
    const int i = d & 31;
    const float val = qr[col];
    const float pval = qr[col ^ 32];
    const float r = (val * cn[i] + ((d < 32) ? -pval : pval) * sn[i]) * 0.125f;
    qh[((size_t)(b * 16 + hh) * 2048 + n) * 64 + d] = f2bf(r);
  } else {
    if (t < 64) {  // k
      const int d = t, i = d & 31;
      const float val = qr[1024 + d];
      const float pval = qr[1024 + (d ^ 32)];
      const float r = val * cn[i] + ((d < 32) ? -pval : pval) * sn[i];
      kh[(size_t)row * 64 + d] = f2bf(r);
    } else if (t < 128) {  // v -> v^T
      const int d = t - 64;
      vt[((size_t)b * 64 + d) * 2048 + n] = f2bf(qr[1088 + d]);
    }
  }
}

// ---------------- SwiGLU in-place: ffraw[:, :8192] = silu(gate)*x ----------------
__global__ __launch_bounds__(256) void silu_kernel(u16* __restrict__ ffraw) {
  const int idx = blockIdx.x * 256 + threadIdx.x;  // one per 4 elems
  const int row = idx >> 11;
  const int c4 = (idx & 2047) * 4;
  u16* px = ffraw + (size_t)row * 16384 + c4;
  const ushort4 xv = *(const ushort4*)px;
  const ushort4 gv = *(const ushort4*)(px + 8192);
  const float xf[4] = {bf2f(xv.x), bf2f(xv.y), bf2f(xv.z), bf2f(xv.w)};
  const float gf[4] = {bf2f(gv.x), bf2f(gv.y), bf2f(gv.z), bf2f(gv.w)};
  u16 res[4];
#pragma unroll
  for (int e = 0; e < 4; ++e) {
    const float s = gf[e] / (1.0f + __expf(-gf[e]));
    res[e] = f2bf(s * xf[e]);
  }
  *(ushort4*)px = make_ushort4(res[0], res[1], res[2], res[3]);
}

// ---------------- causal MQA flash attention ----------------
// grid (32 qblocks, 32 bh); 4 waves, each owns 16 q rows. No LDS, no barriers.
// Swapped QK^T: st = mfma(K_tile, Q^T) so row-softmax reduces via shfl_xor(16/32).
__global__ __launch_bounds__(256) void attn_kernel(const u16* __restrict__ qh, const u16* __restrict__ kh,
                                                   const u16* __restrict__ vt, u16* __restrict__ attn_in) {
  const int qb = blockIdx.x, bh = blockIdx.y;
  const int b = bh >> 4, h = bh & 15;
  const int t = threadIdx.x, w = t >> 6, l = t & 63;
  const int lq = l & 15, g = l >> 4;
  const int qw = qb * 64 + w * 16;
  const u16* qp = qh + ((size_t)bh * 2048 + qw + lq) * 64 + g * 8;
  const bf16x8 qf0 = *(const bf16x8*)qp;
  const bf16x8 qf1 = *(const bf16x8*)(qp + 32);
  const u16* kb = kh + (size_t)b * 2048 * 64;
  const u16* vb = vt + (size_t)b * 64 * 2048;
  f32x4 oacc[4];
  const f32x4 z = {0.f, 0.f, 0.f, 0.f};
#pragma unroll
  for (int c = 0; c < 4; ++c) oacc[c] = z;
  float m_run = -1e30f, l_run = 0.f;
  const int nt = ((qw + 15) >> 5) + 1;
  for (int tile = 0; tile < nt; ++tile) {
    const int kv0 = tile << 5;
    const u16* kp = kb + ((size_t)kv0 + lq) * 64 + g * 8;
    f32x4 st0 = MFMA_B16(*(const bf16x8*)kp, qf0, z);
    st0 = MFMA_B16(*(const bf16x8*)(kp + 32), qf1, st0);
    f32x4 st1 = MFMA_B16(*(const bf16x8*)(kp + 16 * 64), qf0, z);
    st1 = MFMA_B16(*(const bf16x8*)(kp + 16 * 64 + 32), qf1, st1);
    // st{s}[r] = S[q = qw+lq][j = kv0 + s*16 + g*4 + r]
    if (tile == nt - 1) {
      const int iq = qw + lq;
#pragma unroll
      for (int r = 0; r < 4; ++r) {
        if (kv0 + g * 4 + r > iq) st0[r] = -1e30f;
        if (kv0 + 16 + g * 4 + r > iq) st1[r] = -1e30f;
      }
    }
    float pmax = fmaxf(fmaxf(fmaxf(st0[0], st0[1]), fmaxf(st0[2], st0[3])),
                       fmaxf(fmaxf(st1[0], st1[1]), fmaxf(st1[2], st1[3])));
    pmax = fmaxf(pmax, __shfl_xor(pmax, 16));
    pmax = fmaxf(pmax, __shfl_xor(pmax, 32));
    const float mnew = fmaxf(m_run, pmax);
    const float so = __expf(m_run - mnew);
    float p0[4], p1[4];
    float psum = 0.f;
#pragma unroll
    for (int r = 0; r < 4; ++r) {
      p0[r] = __expf(st0[r] - mnew);
      p1[r] = __expf(st1[r] - mnew);
      psum += p0[r] + p1[r];
    }
    psum += __shfl_xor(psum, 16);
    psum += __shfl_xor(psum, 32);
    l_run = l_run * so + psum;
    m_run = mnew;
    float sr[4];
#pragma unroll
    for (int r = 0; r < 4; ++r) sr[r] = __shfl(so, g * 4 + r);
#pragma unroll
    for (int c = 0; c < 4; ++c)
#pragma unroll
      for (int r = 0; r < 4; ++r) oacc[c][r] *= sr[r];
    // redistribute P (C'-layout) into A-fragment layout: lane needs P[q=lq][j=8g+jj]
    bf16x8 pa;
#pragma unroll
    for (int jj = 0; jj < 8; ++jj) {
      const int srcl = ((((g & 1) * 8 + jj) >> 2) << 4) + lq;
      const float v0 = __shfl(p0[jj & 3], srcl);
      const float v1 = __shfl(p1[jj & 3], srcl);
      pa[jj] = (__bf16)((g >= 2) ? v1 : v0);
    }
    const u16* vp = vb + (size_t)lq * 2048 + kv0 + g * 8;
#pragma unroll
    for (int c = 0; c < 4; ++c)
      oacc[c] = MFMA_B16(pa, *(const bf16x8*)(vp + (size_t)c * 16 * 2048), oacc[c]);
  }
  const float inv = 1.0f / l_run;
  float ir[4];
#pragma unroll
  for (int r = 0; r < 4; ++r) ir[r] = __shfl(inv, g * 4 + r);
#pragma unroll
  for (int c = 0; c < 4; ++c)
#pragma unroll
    for (int r = 0; r < 4; ++r) {
      const int n = qw + g * 4 + r;
      attn_in[((size_t)b * 2048 + n) * 1024 + h * 64 + c * 16 + lq] = f2bf(oacc[c][r] * ir[r]);
    }
}

// ---------------- oa = attn_in @ a_o (4096 x 8) ----------------
__global__ __launch_bounds__(256) void oa_kernel(const u16* __restrict__ attn_in, const float* __restrict__ a_o,
                                                 float* __restrict__ oa) {
  const int row = blockIdx.x, t = threadIdx.x;
  float acc[8];
#pragma unroll
  for (int j = 0; j < 8; ++j) acc[j] = 0.f;
  const u16* xr = attn_in + (size_t)row * 1024;
  for (int k = t; k < 1024; k += 256) {
    const float xv = bf2f(xr[k]);
    const float* ap = a_o + k * 8;
#pragma unroll
    for (int j = 0; j < 8; ++j) acc[j] += xv * ap[j];
  }
#pragma unroll
  for (int j = 0; j < 8; ++j) {
    float vv = acc[j];
#pragma unroll
    for (int o = 32; o > 0; o >>= 1) vv += __shfl_xor(vv, o);
    acc[j] = vv;
  }
  __shared__ float red[4][8];
  if ((t & 63) == 0) {
#pragma unroll
    for (int j = 0; j < 8; ++j) red[t >> 6][j] = acc[j];
  }
  __syncthreads();
  if (t < 8) oa[(size_t)row * 8 + t] = red[0][t] + red[1][t] + red[2][t] + red[3][t];
}

// ---------------- output GEMM: attn_in @ waoT + ffact @ wfoT + oa@b_o ----------------
__global__ __launch_bounds__(256) void gemm_out_kernel(const u16* __restrict__ A1, const u16* __restrict__ B1T,
                                                       const u16* __restrict__ A2, const u16* __restrict__ B2T,
                                                       const float* __restrict__ oa, const float* __restrict__ b_o,
                                                       float* __restrict__ outp) {
  __shared__ u16 lds_a[128 * 32];
  __shared__ u16 lds_b[64 * 32];
  const int bm = blockIdx.x, bn = blockIdx.y;
  const int t = threadIdx.x, w = t >> 6, l = t & 63;
  const int wr = w >> 1, wc = w & 1, lq = l & 15, g = l >> 4;
  f32x4 acc[4][2];
  const f32x4 z = {0.f, 0.f, 0.f, 0.f};
#pragma unroll
  for (int mi = 0; mi < 4; ++mi)
#pragma unroll
    for (int ni = 0; ni < 2; ++ni) acc[mi][ni] = z;
  gemm_phase(A1 + (size_t)bm * 128 * 1024, 1024, B1T + (size_t)bn * 64 * 1024, 1024, 1024,
             lds_a, lds_b, acc, t, wr, wc, lq, g);
  gemm_phase(A2 + (size_t)bm * 128 * 16384, 16384, B2T + (size_t)bn * 64 * 8192, 8192, 8192,
             lds_a, lds_b, acc, t, wr, wc, lq, g);
  const int rowbase = bm * 128 + wr * 64;
  const int colbase = bn * 64 + wc * 32;
#pragma unroll
  for (int mi = 0; mi < 4; ++mi)
#pragma unroll
    for (int ni = 0; ni < 2; ++ni)
#pragma unroll
      for (int r = 0; r < 4; ++r) {
        const int grow = rowbase + mi * 16 + g * 4 + r;
        const int gcol = colbase + ni * 16 + lq;
        const float* oar = oa + (size_t)grow * 8;
        const float* bp = b_o + gcol;
        float add = 0.f;
#pragma unroll
        for (int j = 0; j < 8; ++j) add += oar[j] * bp[j * 2048];
        outp[(size_t)grow * 2048 + gcol] = acc[mi][ni][r] + add;
      }
}

// ---------------- launch ----------------
extern "C" void kernel_launch(void* const* d_in, const int* in_sizes, int n_in,
                              void* d_out, int out_size, void* d_ws, size_t ws_size,
                              hipStream_t stream) {
  const float* x = (const float*)d_in[0];
  const float* gamma = (const float*)d_in[1];
  const float* w_fused = (const float*)d_in[2];
  const float* w_attn_out = (const float*)d_in[3];
  const float* w_ff_out = (const float*)d_in[4];
  const float* a_q = (const float*)d_in[5];
  const float* b_q = (const float*)d_in[6];
  const float* a_k = (const float*)d_in[7];
  const float* b_k = (const float*)d_in[8];
  const float* a_v = (const float*)d_in[9];
  const float* b_v = (const float*)d_in[10];
  const float* a_o = (const float*)d_in[11];
  const float* b_o = (const float*)d_in[12];
  float* outp = (float*)d_out;
  char* ws = (char*)d_ws;
  if (ws_size < WS_NEED) return;  // fail loudly (out stays poisoned)

  u16* wfT = (u16*)(ws + OFF_WFT);
  u16* waoT = (u16*)(ws + OFF_WAOT);
  u16* wfoT = (u16*)(ws + OFF_WFOT);
  u16* xn = (u16*)(ws + OFF_XN);
  float* xa = (float*)(ws + OFF_XA);
  float* qkv = (float*)(ws + OFF_QKV);
  u16* ffraw = (u16*)(ws + OFF_FFRAW);
  u16* qh = (u16*)(ws + OFF_QH);
  u16* kh = (u16*)(ws + OFF_KH);
  u16* vt = (u16*)(ws + OFF_VT);
  u16* ain = (u16*)(ws + OFF_AIN);
  float* oa = (float*)(ws + OFF_OA);
  float* cosT = (float*)(ws + OFF_COS);
  float* sinT = (float*)(ws + OFF_SIN);

  transpose_cast_kernel<<<dim3(548, 64), dim3(32, 8), 0, stream>>>(w_fused, wfT, 2048, 17536);
  transpose_cast_kernel<<<dim3(64, 32), dim3(32, 8), 0, stream>>>(w_attn_out, waoT, 1024, 2048);
  transpose_cast_kernel<<<dim3(64, 256), dim3(32, 8), 0, stream>>>(w_ff_out, wfoT, 8192, 2048);
  rope_table_kernel<<<2048, 64, 0, stream>>>(cosT, sinT);
  layernorm_kernel<<<4096, 256, 0, stream>>>(x, gamma, xn);
  xa3_kernel<<<4096, 256, 0, stream>>>(xn, a_q, a_k, a_v, xa);
  gemm_fused_kernel<<<dim3(32, 274), 256, 0, stream>>>(xn, wfT, qkv, ffraw, xa, b_q, b_k, b_v);
  rope_qkv_kernel<<<dim3(4096, 5), 256, 0, stream>>>(qkv, cosT, sinT, qh, kh, vt);
  silu_kernel<<<32768, 256, 0, stream>>>(ffraw);
  attn_kernel<<<dim3(32, 32), 256, 0, stream>>>(qh, kh, vt, ain);
  oa_kernel<<<4096, 256, 0, stream>>>(ain, a_o, oa);
  gemm_out_kernel<<<dim3(32, 32), 256, 0, stream>>>(ain, waoT, ffraw, wfoT, oa, b_o, outp);
}